// Round 3
// baseline (384.060 us; speedup 1.0000x reference)
//
#include <hip/hip_runtime.h>
#include <hip/hip_bf16.h>

// Problem constants (from reference): NV=4096, NH=4096, N=8192, h=0, p=1.
// Inputs: mu (f32, N), var (f32, N*N). Output: muTE (f32, N) ++ M (f32, N*N).
// N = 8192 = 2^13.
#define NN 8192L

// ---------------------------------------------------------------------------
// Single fused kernel: every float4 of the output is written exactly once.
// Layout (element index e = 4*i):
//   e in [0, N)        : muTE  -> {hp, -hp, 0, 0, ...} only first float4 nonzero
//   e in [N, N+N*N)    : M, m = e-N, r = m>>13, c = m&8191
//     r==0           : M[0,j] = v[j]   (j==0 -> 2*n3_hhp+hp, j==1 -> chp)
//     r==1           : M[1,j] = -v[j]  (j==0 -> chp, j==1 -> -2*n3_pph+hp)
//     r>=2 && c==0   : {v[r], -v[r], 0, 0}
//     else           : zeros  (the 99.96% fast path, wave-uniform branch)
// v[j] = -2*mu[j]*mu1*mu0 + mu[j]*var[1,0] + mu1*var[j,0] + mu0*var[j,1],
// v[0]=v[1]=0. All math f32, matching the np reference exactly.
// ---------------------------------------------------------------------------
__global__ void eatrxn_fused_kernel(const float* __restrict__ mu,
                                    const float* __restrict__ var,
                                    float* __restrict__ out, long n16) {
    long i = (long)blockIdx.x * blockDim.x + threadIdx.x;
    const long stride = (long)gridDim.x * blockDim.x;
    const long N = NN;

    for (; i < n16; i += stride) {
        long e = i * 4;
        float4 val;
        val.x = 0.0f; val.y = 0.0f; val.z = 0.0f; val.w = 0.0f;

        if (e >= 3 * N) {
            // Fast path region: M rows >= 2. Only c==0 is special.
            long m = e - N;
            long c = m & (N - 1);
            if (c == 0) {
                long r = m >> 13;
                float mu0 = mu[0], mu1 = mu[1];
                float var10 = var[N];          // nvar[p,h]
                float muj = mu[r];
                float vj0 = var[r * N];        // nvar[r,h]
                float vj1 = var[r * N + 1];    // nvar[r,p]
                float v = -2.0f * muj * mu1 * mu0 + muj * var10
                          + mu1 * vj0 + mu0 * vj1;
                val.x = v;                     // M[r,0]
                val.y = -v;                    // M[r,1]
            }
        } else {
            // Slow path: muTE (e < N) or M rows 0/1. Only 6144 float4s total.
            float mu0   = mu[0];
            float mu1   = mu[1];
            float var00 = var[0];
            float var01 = var[1];              // hp
            float var10 = var[N];
            float var11 = var[N + 1];
            float hp = var01;
            float n3_hhp = -2.0f * mu0 * mu0 * mu1 + 2.0f * mu0 * var01 + mu1 * var00;
            float n3_hpp = -2.0f * mu0 * mu1 * mu1 + mu0 * var11 + 2.0f * mu1 * var01;
            float n3_pph = -2.0f * mu1 * mu1 * mu0 + 2.0f * mu1 * var10 + mu0 * var11;
            float chp = -n3_hhp + n3_hpp - hp;

            float vv[4];
            #pragma unroll
            for (int k = 0; k < 4; ++k) {
                long ek = e + k;
                float r_ = 0.0f;
                if (ek < N) {
                    // muTE
                    r_ = (ek == 0) ? hp : ((ek == 1) ? -hp : 0.0f);
                } else {
                    long m = ek - N;
                    long r = m >> 13;
                    long j = m & (N - 1);
                    float v;
                    if (j < 2) {
                        v = 0.0f;
                    } else {
                        float muj = mu[j];
                        float vj0 = var[j * N];
                        float vj1 = var[j * N + 1];
                        v = -2.0f * muj * mu1 * mu0 + muj * var10
                            + mu1 * vj0 + mu0 * vj1;
                    }
                    if (r == 0) {
                        r_ = (j == 0) ? (2.0f * n3_hhp + hp)
                           : (j == 1) ? chp
                           : v;
                    } else { // r == 1
                        r_ = (j == 0) ? chp
                           : (j == 1) ? (-2.0f * n3_pph + hp)
                           : -v;
                    }
                }
                vv[k] = r_;
            }
            val.x = vv[0]; val.y = vv[1]; val.z = vv[2]; val.w = vv[3];
        }

        ((float4*)out)[i] = val;
    }
}

extern "C" void kernel_launch(void* const* d_in, const int* in_sizes, int n_in,
                              void* d_out, int out_size, void* d_ws, size_t ws_size,
                              hipStream_t stream) {
    const float* mu  = (const float*)d_in[0];
    const float* var = (const float*)d_in[1];
    float* out = (float*)d_out;

    // (NN + NN*NN) f32 = 268,468,224 bytes = 16,779,264 float4 stores.
    long n16 = (NN + NN * NN) / 4;
    eatrxn_fused_kernel<<<8192, 256, 0, stream>>>(mu, var, out, n16);
}